// Round 12
// baseline (279.840 us; speedup 1.0000x reference)
//
#include <hip/hip_runtime.h>
#include <hip/hip_bf16.h>
#include <math.h>

#define F 128
#define NBLK 256      // blocks for bucket_count / bucket_scatter
#define MAXNB 2048    // max buckets (N up to 131072 at 64 nodes/bucket)
#define CMASK 0x03FFFFFFu   // pairs payload mask (src id); bits 26..31 = bucket-local dst

typedef short bf16x8 __attribute__((ext_vector_type(8)));
typedef float f32x4 __attribute__((ext_vector_type(4)));
typedef float f32x2 __attribute__((ext_vector_type(2)));

__device__ __forceinline__ int rfl(int v) { return __builtin_amdgcn_readfirstlane(v); }
__device__ __forceinline__ unsigned short f2bf(float f) {
    __hip_bfloat16 h = __float2bfloat16(f);
    return *reinterpret_cast<unsigned short*>(&h);
}
__device__ __forceinline__ unsigned pack2(float lo, float hi) {
    return (unsigned)f2bf(lo) | ((unsigned)f2bf(hi) << 16);
}

// ---------------- CSR build via counting sort (zero global atomics) ----------------

// K1: per-(block,bucket) histogram. Block b owns contiguous edge chunk.
__global__ __launch_bounds__(256) void bucket_count(
    const int* __restrict__ dst, int E, int NB, int chunk, int* __restrict__ hist2)
{
    __shared__ int h[MAXNB];
    for (int j = threadIdx.x; j < NB; j += 256) h[j] = 0;
    __syncthreads();
    int b = blockIdx.x;
    int beg = b * chunk, end = min(E, beg + chunk);
    for (int e = beg + threadIdx.x; e < end; e += 256)
        atomicAdd(&h[dst[e] >> 6], 1);             // LDS atomic
    __syncthreads();
    for (int j = threadIdx.x; j < NB; j += 256) hist2[b * NB + j] = h[j];
}

// K2a: per-bucket: exclusive scan over the 256 block-counts (in place) + totals.
__global__ __launch_bounds__(256) void bucket_sumscan(
    int* __restrict__ hist2, int NB, int N,
    int* __restrict__ ptot, int* __restrict__ ctot)
{
    __shared__ int wsum[4];
    int j = blockIdx.x;
    int t = threadIdx.x;                 // = staging block b
    int v = hist2[t * NB + j];
    int lane = t & 63, w = t >> 6;
    int s = v;
#pragma unroll
    for (int off = 1; off < 64; off <<= 1) {
        int u = __shfl_up(s, off);
        if (lane >= off) s += u;
    }
    if (lane == 63) wsum[w] = s;
    __syncthreads();
    int wbase = 0;
    for (int i = 0; i < w; ++i) wbase += wsum[i];
    hist2[t * NB + j] = wbase + s - v;   // exclusive, within bucket
    if (t == 255) {
        int tot = wbase + s;
        ptot[j] = tot;
        int n0 = j << 6;
        int nodes = min(64, N - n0);
        ctot[j] = tot + nodes;           // + self-loops
    }
}

// K2b: exclusive scan of bucket totals -> pairbase / colbase.
__global__ __launch_bounds__(1024) void base_scan(
    const int* __restrict__ ptot, const int* __restrict__ ctot, int NB,
    int* __restrict__ pairbase, int* __restrict__ colbase)
{
    __shared__ int pt[MAXNB], ct[MAXNB];
    int t = threadIdx.x;
    for (int j = t; j < MAXNB; j += 1024) {
        pt[j] = (j < NB) ? ptot[j] : 0;
        ct[j] = (j < NB) ? ctot[j] : 0;
    }
    __syncthreads();
    for (int off = 1; off < MAXNB; off <<= 1) {
        int i0 = t, i1 = t + 1024;
        int a0 = (i0 >= off) ? pt[i0 - off] : 0;
        int c0 = (i0 >= off) ? ct[i0 - off] : 0;
        int a1 = (i1 >= off) ? pt[i1 - off] : 0;
        int c1 = (i1 >= off) ? ct[i1 - off] : 0;
        __syncthreads();
        pt[i0] += a0; ct[i0] += c0;
        pt[i1] += a1; ct[i1] += c1;
        __syncthreads();
    }
    for (int j = t; j < NB; j += 1024) {
        pairbase[j] = j ? pt[j - 1] : 0;
        colbase[j]  = j ? ct[j - 1] : 0;
    }
    if (t == 0) { pairbase[NB] = pt[NB - 1]; colbase[NB] = ct[NB - 1]; }
}

// K3: scatter tagged (src | localdst<<26) into bucket regions (4B entries).
__global__ __launch_bounds__(256) void bucket_scatter(
    const int* __restrict__ src, const int* __restrict__ dst, int E, int NB, int chunk,
    const int* __restrict__ gbase2, const int* __restrict__ pairbase,
    unsigned* __restrict__ pairs)
{
    __shared__ int ofs[MAXNB];
    int b = blockIdx.x;
    for (int j = threadIdx.x; j < NB; j += 256)
        ofs[j] = gbase2[b * NB + j] + pairbase[j];
    __syncthreads();
    int beg = b * chunk, end = min(E, beg + chunk);
    for (int e = beg + threadIdx.x; e < end; e += 256) {
        int s = src[e], d = dst[e];
        int slot = atomicAdd(&ofs[d >> 6], 1);     // LDS atomic
        pairs[slot] = (unsigned)s | ((unsigned)(d & 63) << 26);
    }
}

// K4: per-bucket node-CSR: rp, dinv, self-loop, col scatter (col = pure src id).
__global__ __launch_bounds__(256) void bucket_csr(
    const unsigned* __restrict__ pairs, const int* __restrict__ pairbase,
    const int* __restrict__ colbase, int N, int E,
    int* __restrict__ rp, unsigned* __restrict__ col, float* __restrict__ dinv)
{
    __shared__ int cnt[64], fill[64], seg[64];
    int j = blockIdx.x;
    int t = threadIdx.x;
    if (t < 64) { cnt[t] = 0; fill[t] = 0; }
    __syncthreads();
    int beg = pairbase[j], end = pairbase[j + 1];
    int n0 = j << 6;
    for (int e = beg + t; e < end; e += 256)
        atomicAdd(&cnt[pairs[e] >> 26], 1);
    __syncthreads();
    if (t < 64) {
        int c = cnt[t];
        int v = c + 1;                 // + self-loop
#pragma unroll
        for (int off = 1; off < 64; off <<= 1) {
            int u = __shfl_up(v, off);
            if (t >= off) v += u;
        }
        int segb = colbase[j] + v - (c + 1);   // exclusive scan base
        int n = n0 + t;
        if (n < N) {
            seg[t] = segb;
            rp[n] = segb;
            dinv[n] = rsqrtf((float)(c + 1));
            col[segb + c] = (unsigned)n;       // self-loop at segment end
            if (n == N - 1) rp[N] = segb + c + 1;
        }
    }
    __syncthreads();
    for (int e = beg + t; e < end; e += 256) {
        unsigned pr = pairs[e];
        int ln = (int)(pr >> 26);
        int r = atomicAdd(&fill[ln], 1);       // LDS atomic
        col[seg[ln] + r] = pr & CMASK;
    }
}

// ------- W1 -> bf16, transposed [j][k], XOR-swizzled bytes (once) -------
__global__ void w1prep(const float* __restrict__ W1, unsigned char* __restrict__ W1t) {
    int tid = blockIdx.x * blockDim.x + threadIdx.x;   // tid = j*128 + k
    if (tid >= F * F) return;
    int j = tid >> 7, k = tid & 127;
    unsigned short w = f2bf(W1[k * F + j]);
    int ofs = (j << 8) + (((k << 1)) ^ ((j & 7) << 4));
    *reinterpret_cast<unsigned short*>(W1t + ofs) = w;
}

// ------- prescale: xsq[p][n][32] = fp8(dinv[n]*x[n][32p..32p+31]) -------
__global__ void prescale(const float* __restrict__ x, const float* __restrict__ dinv,
                         unsigned char* __restrict__ xsq, int N) {
    int i = blockIdx.x * blockDim.x + threadIdx.x;   // float4 group: n*32+g
    if (i >= N * 32) return;
    int n = i >> 5, g = i & 31;
    int p = g >> 3, q = g & 7;
    float d = dinv[n];
    float4 v = ((const float4*)x)[i];
    int r = __builtin_amdgcn_cvt_pk_fp8_f32(v.x * d, v.y * d, 0, false);
    r = __builtin_amdgcn_cvt_pk_fp8_f32(v.z * d, v.w * d, r, true);
    *reinterpret_cast<unsigned*>(xsq + (size_t)p * N * 32 + (size_t)n * 32 + 4 * q) = r;
}

#define ACC16(u) \
    acc0 += __builtin_amdgcn_cvt_pk_f32_fp8((u).x, false); \
    acc1 += __builtin_amdgcn_cvt_pk_f32_fp8((u).x, true);  \
    acc2 += __builtin_amdgcn_cvt_pk_f32_fp8((u).y, false); \
    acc3 += __builtin_amdgcn_cvt_pk_f32_fp8((u).y, true);  \
    acc4 += __builtin_amdgcn_cvt_pk_f32_fp8((u).z, false); \
    acc5 += __builtin_amdgcn_cvt_pk_f32_fp8((u).z, true);  \
    acc6 += __builtin_amdgcn_cvt_pk_f32_fp8((u).w, false); \
    acc7 += __builtin_amdgcn_cvt_pk_f32_fp8((u).w, true);

// ------- agg1 v8: lane-pair/16B loop; ONE PASS PER DISPATCH (kernel = pass) -------
// Kernel boundary guarantees only one 3.2MB xsq quarter is live chip-wide ->
// L2-resident with no pinning logic. 128 threads = 2 waves = 64 nodes/block.
__global__ __launch_bounds__(128, 4) void agg1(
    const unsigned char* __restrict__ xsq, const int* __restrict__ rp,
    const unsigned* __restrict__ col, const float* __restrict__ dinv,
    unsigned short* __restrict__ xa, int N, int p)
{
    int w = threadIdx.x >> 6, l = threadIdx.x & 63;
    int s = l >> 1;                        // node within wave (0..31)
    int c16 = l & 1;                       // which 16B half of the 32B quarter-row
    int node = blockIdx.x * 64 + w * 32 + s;
    const unsigned char* xsp = xsq + (size_t)p * N * 32;

    bool valid = node < N;
    int beg = valid ? rp[node] : 0;
    int end = valid ? rp[node + 1] : 0;
    int cnt = end - beg;
    const unsigned* cp = col + beg;
    int boff = c16 << 4;

    f32x2 acc0 = {0.f,0.f}, acc1 = {0.f,0.f}, acc2 = {0.f,0.f}, acc3 = {0.f,0.f};
    f32x2 acc4 = {0.f,0.f}, acc5 = {0.f,0.f}, acc6 = {0.f,0.f}, acc7 = {0.f,0.f};
    int k = 0;
    for (; k + 4 <= cnt; k += 4) {
        unsigned cv0 = cp[k], cv1 = cp[k+1], cv2 = cp[k+2], cv3 = cp[k+3];
        uint4 u0 = *reinterpret_cast<const uint4*>(xsp + ((size_t)cv0 << 5) + boff);
        uint4 u1 = *reinterpret_cast<const uint4*>(xsp + ((size_t)cv1 << 5) + boff);
        uint4 u2 = *reinterpret_cast<const uint4*>(xsp + ((size_t)cv2 << 5) + boff);
        uint4 u3 = *reinterpret_cast<const uint4*>(xsp + ((size_t)cv3 << 5) + boff);
        ACC16(u0) ACC16(u1) ACC16(u2) ACC16(u3)
    }
    for (; k < cnt; ++k) {
        unsigned cv = cp[k];
        uint4 u = *reinterpret_cast<const uint4*>(xsp + ((size_t)cv << 5) + boff);
        ACC16(u)
    }

    if (valid) {
        float d = dinv[node];
        unsigned q0 = pack2(acc0.x * d, acc0.y * d);
        unsigned q1 = pack2(acc1.x * d, acc1.y * d);
        unsigned q2 = pack2(acc2.x * d, acc2.y * d);
        unsigned q3 = pack2(acc3.x * d, acc3.y * d);
        unsigned q4 = pack2(acc4.x * d, acc4.y * d);
        unsigned q5 = pack2(acc5.x * d, acc5.y * d);
        unsigned q6 = pack2(acc6.x * d, acc6.y * d);
        unsigned q7 = pack2(acc7.x * d, acc7.y * d);
        unsigned short* op = xa + (size_t)node * F + p * 32 + (c16 << 4);
        *reinterpret_cast<uint4*>(op)     = make_uint4(q0, q1, q2, q3);
        *reinterpret_cast<uint4*>(op + 8) = make_uint4(q4, q5, q6, q7);
    }
}

// ------- MLP: h2s[i] = dinv_i * (relu(xa@W1 + b1) @ W2) via MFMA -------
__global__ __launch_bounds__(512) void mlp(
    const unsigned short* __restrict__ xa, const float* __restrict__ dinv,
    const float* __restrict__ b1, const float* __restrict__ W2,
    const unsigned char* __restrict__ W1t_g, float* __restrict__ h2s, int N)
{
    __shared__ unsigned char W1t[F * F * 2];   // 32 KB swizzled [j][k]
    __shared__ unsigned char XA[32 * 256];     // 8 KB swizzled [node][k]
    __shared__ float part[2][16][4];

    for (int idx = threadIdx.x; idx < (F * F * 2) / 16; idx += 512)
        ((int4*)W1t)[idx] = ((const int4*)W1t_g)[idx];

    {
        int r = threadIdx.x >> 4, t16 = threadIdx.x & 15;
        int gi = blockIdx.x * 32 + r;
        uint4 v = make_uint4(0, 0, 0, 0);
        if (gi < N) v = *reinterpret_cast<const uint4*>(xa + (size_t)gi * F + 8 * t16);
        *reinterpret_cast<uint4*>(XA + r * 256 + ((16 * t16) ^ ((r & 7) << 4))) = v;
    }
    __syncthreads();

    int wave = threadIdx.x >> 6, lane = threadIdx.x & 63;
    int g = wave >> 2, jt0 = (wave & 3) * 2;
    int l15 = lane & 15;
    int kb = (lane >> 4) * 16;

    bf16x8 afr[4];
    int arow = g * 16 + l15;
#pragma unroll
    for (int kk = 0; kk < 4; ++kk) {
        int ofs = arow * 256 + ((kk * 64 + kb) ^ ((arow & 7) << 4));
        afr[kk] = *reinterpret_cast<const bf16x8*>(XA + ofs);
    }

    float p[4] = {0.f, 0.f, 0.f, 0.f};
#pragma unroll
    for (int jj = 0; jj < 2; ++jj) {
        int j = (jt0 + jj) * 16 + l15;
        f32x4 d = {0.f, 0.f, 0.f, 0.f};
#pragma unroll
        for (int kk = 0; kk < 4; ++kk) {
            int ofs = j * 256 + ((kk * 64 + kb) ^ ((j & 7) << 4));
            bf16x8 bfr = *reinterpret_cast<const bf16x8*>(W1t + ofs);
            d = __builtin_amdgcn_mfma_f32_16x16x32_bf16(afr[kk], bfr, d, 0, 0, 0);
        }
        float bj = b1[j], wj = W2[j];
#pragma unroll
        for (int r = 0; r < 4; ++r) {
            float v = fmaxf(d[r] + bj, 0.f);
            p[r] += v * wj;
        }
    }
#pragma unroll
    for (int r = 0; r < 4; ++r) {
        p[r] += __shfl_xor(p[r], 1);
        p[r] += __shfl_xor(p[r], 2);
        p[r] += __shfl_xor(p[r], 4);
        p[r] += __shfl_xor(p[r], 8);
    }
    if (l15 == 0) {
#pragma unroll
        for (int r = 0; r < 4; ++r)
            part[g][(lane >> 4) * 4 + r][wave & 3] = p[r];
    }
    __syncthreads();

    if (threadIdx.x < 32) {
        int i = blockIdx.x * 32 + threadIdx.x;
        if (i < N) {
            const float* q = part[threadIdx.x >> 4][threadIdx.x & 15];
            h2s[i] = dinv[i] * (q[0] + q[1] + q[2] + q[3]);
        }
    }
}

// ------- layer 2 aggregation: quarter-wave (16 lanes) per node -------
__global__ __launch_bounds__(256) void agg2(
    const float* __restrict__ h2s, const int* __restrict__ rp,
    const unsigned* __restrict__ col, const float* __restrict__ dinv,
    const float* __restrict__ b2, float* __restrict__ h2, int N)
{
    int nid = (blockIdx.x * 256 + threadIdx.x) >> 4;
    int c = threadIdx.x & 15;
    if (nid >= N) return;
    int beg = rfl(rp[nid]);
    int end = rfl(rp[nid + 1]);
    float s = 0.f;
    for (int e = beg + c; e < end; e += 16)
        s += h2s[col[e]];
#pragma unroll
    for (int off = 8; off; off >>= 1) s += __shfl_xor(s, off);
    if (c == 0) h2[nid] = dinv[nid] * s + b2[0];
}

// ------- edge probabilities -------
__global__ void edge_probs(const int* __restrict__ src, const int* __restrict__ dst,
                           const float* __restrict__ h2, float* __restrict__ out, int E) {
    int e = blockIdx.x * blockDim.x + threadIdx.x;
    if (e >= E) return;
    float v = h2[src[e]] * h2[dst[e]];
    out[e] = 1.0f / (1.0f + __expf(-v));
}

// ---------------- launch ----------------

extern "C" void kernel_launch(void* const* d_in, const int* in_sizes, int n_in,
                              void* d_out, int out_size, void* d_ws, size_t ws_size,
                              hipStream_t stream) {
    const float* x  = (const float*)d_in[0];
    const int*   ei = (const int*)d_in[1];       // int32 (JAX x64 disabled)
    const float* W1 = (const float*)d_in[2];
    const float* b1 = (const float*)d_in[3];
    const float* W2 = (const float*)d_in[4];
    const float* b2 = (const float*)d_in[5];
    float* out = (float*)d_out;

    int N = in_sizes[0] / F;
    int E = in_sizes[1] / 2;
    const int* src = ei;
    const int* dst = ei + E;
    int total = E + N;
    int NB = (N + 63) >> 6;                      // buckets of 64 nodes (CSR build)
    int chunk = (E + NBLK - 1) / NBLK;

    // workspace; pairs (4B/edge) and xsq share one region
    char* ws = (char*)d_ws;
    size_t off = 0;
    auto alloc = [&](size_t bytes) -> void* {
        off = (off + 255) & ~(size_t)255;
        void* p = ws + off;
        off += bytes;
        return p;
    };
    float* dinv  = (float*)alloc((size_t)N * 4);
    int*   rp    = (int*)alloc((size_t)(N + 1) * 4);
    int*   hist2 = (int*)alloc((size_t)NBLK * NB * 4);
    int*   colbase  = (int*)alloc((size_t)(NB + 1) * 4);
    int*   pairbase = (int*)alloc((size_t)(NB + 1) * 4);
    int*   ptot  = (int*)alloc((size_t)NB * 4);
    int*   ctot  = (int*)alloc((size_t)NB * 4);
    unsigned* col = (unsigned*)alloc((size_t)total * 4);
    unsigned char* W1tg = (unsigned char*)alloc(F * F * 2);
    unsigned short* xa  = (unsigned short*)alloc((size_t)N * F * 2);
    float* h2s   = (float*)alloc((size_t)N * 4);
    float* h2    = (float*)alloc((size_t)N * 4);
    size_t uniBytes = (size_t)E * 4;             // pairs (tagged, 4B)
    size_t xsqBytes = (size_t)N * 32 * 4;
    if (xsqBytes > uniBytes) uniBytes = xsqBytes;
    void* uni = alloc(uniBytes);
    unsigned* pairs = (unsigned*)uni;
    unsigned char* xsq = (unsigned char*)uni;
    (void)ws_size;

    bucket_count<<<NBLK, 256, 0, stream>>>(dst, E, NB, chunk, hist2);
    bucket_sumscan<<<NB, 256, 0, stream>>>(hist2, NB, N, ptot, ctot);
    base_scan<<<1, 1024, 0, stream>>>(ptot, ctot, NB, pairbase, colbase);
    bucket_scatter<<<NBLK, 256, 0, stream>>>(src, dst, E, NB, chunk, hist2, pairbase, pairs);
    bucket_csr<<<NB, 256, 0, stream>>>(pairs, pairbase, colbase, N, E, rp, col, dinv);
    w1prep<<<(F * F + 255) / 256, 256, 0, stream>>>(W1, W1tg);
    prescale<<<(N * 32 + 255) / 256, 256, 0, stream>>>(x, dinv, xsq, N);
    int nblk1 = (N + 63) / 64;
    for (int p = 0; p < 4; ++p)
        agg1<<<nblk1, 128, 0, stream>>>(xsq, rp, col, dinv, xa, N, p);
    mlp<<<(N + 31) / 32, 512, 0, stream>>>(xa, dinv, b1, W2, W1tg, h2s, N);
    agg2<<<((size_t)N * 16 + 255) / 256, 256, 0, stream>>>(h2s, rp, col, dinv, b2, h2, N);
    edge_probs<<<(E + 255) / 256, 256, 0, stream>>>(src, dst, h2, out, E);
}

// Round 13
// 277.842 us; speedup vs baseline: 1.0072x; 1.0072x over previous
//
#include <hip/hip_runtime.h>
#include <hip/hip_bf16.h>
#include <math.h>

#define F 128
#define NBLK 1024     // blocks for bucket_count / bucket_scatter
#define MAXNB 2048    // max buckets (N up to 131072 at 64 nodes/bucket)
#define CMASK 0x03FFFFFFu   // pairs payload mask (src id); bits 26..31 = bucket-local dst
// hist2 tiled layout: [j/16][t][j%16]  -> every access line-coalesced
#define HIDX(b, j) ((((j) >> 4) * (NBLK * 16)) + ((b) * 16) + ((j) & 15))

typedef short bf16x8 __attribute__((ext_vector_type(8)));
typedef float f32x4 __attribute__((ext_vector_type(4)));
typedef float f32x2 __attribute__((ext_vector_type(2)));

__device__ __forceinline__ int rfl(int v) { return __builtin_amdgcn_readfirstlane(v); }
__device__ __forceinline__ unsigned short f2bf(float f) {
    __hip_bfloat16 h = __float2bfloat16(f);
    return *reinterpret_cast<unsigned short*>(&h);
}
__device__ __forceinline__ unsigned pack2(float lo, float hi) {
    return (unsigned)f2bf(lo) | ((unsigned)f2bf(hi) << 16);
}

// ---------------- CSR build via counting sort (zero global atomics) ----------------

// K1: per-(block,bucket) histogram. Block b owns contiguous edge chunk.
__global__ __launch_bounds__(256) void bucket_count(
    const int* __restrict__ dst, int E, int NBP, int chunk, int* __restrict__ hist2)
{
    __shared__ int h[MAXNB];
    for (int j = threadIdx.x; j < NBP; j += 256) h[j] = 0;
    __syncthreads();
    int b = blockIdx.x;
    int beg = b * chunk, end = min(E, beg + chunk);
    for (int e = beg + threadIdx.x; e < end; e += 256)
        atomicAdd(&h[dst[e] >> 6], 1);             // LDS atomic
    __syncthreads();
    for (int j = threadIdx.x; j < NBP; j += 256) hist2[HIDX(b, j)] = h[j];
}

// K2a: per-tile (16 buckets) scan over the 1024 block-counts, in place; totals out.
__global__ __launch_bounds__(1024) void tile_scan(
    int* __restrict__ hist2, int NB, int N,
    int* __restrict__ ptot, int* __restrict__ ctot)
{
    __shared__ int lds[64][16];
    int tile = blockIdx.x;
    int c = threadIdx.x >> 4, jj = threadIdx.x & 15;
    int j = tile * 16 + jj;
    int* base = hist2 + (size_t)tile * (NBLK * 16);
    // pass 1: local sums over t in [16c, 16c+16)
    int s = 0;
#pragma unroll
    for (int t = c * 16; t < c * 16 + 16; ++t) s += base[t * 16 + jj];
    lds[c][jj] = s;
    __syncthreads();
    // inclusive scan over c (64 chunks), 16 independent columns
    for (int off = 1; off < 64; off <<= 1) {
        int v = (c >= off) ? lds[c - off][jj] : 0;
        __syncthreads();
        lds[c][jj] += v;
        __syncthreads();
    }
    int run = c ? lds[c - 1][jj] : 0;
    // pass 2: write back exclusive prefixes
#pragma unroll
    for (int t = c * 16; t < c * 16 + 16; ++t) {
        int v = base[t * 16 + jj];
        base[t * 16 + jj] = run;
        run += v;
    }
    if (c == 63 && j < NB) {
        int tot = lds[63][jj];
        ptot[j] = tot;
        int n0 = j << 6;
        int nodes = min(64, N - n0);
        ctot[j] = tot + nodes;           // + self-loops
    }
}

// K2b: exclusive scan of bucket totals -> pairbase / colbase.
__global__ __launch_bounds__(1024) void base_scan(
    const int* __restrict__ ptot, const int* __restrict__ ctot, int NB,
    int* __restrict__ pairbase, int* __restrict__ colbase)
{
    __shared__ int pt[MAXNB], ct[MAXNB];
    int t = threadIdx.x;
    for (int j = t; j < MAXNB; j += 1024) {
        pt[j] = (j < NB) ? ptot[j] : 0;
        ct[j] = (j < NB) ? ctot[j] : 0;
    }
    __syncthreads();
    for (int off = 1; off < MAXNB; off <<= 1) {
        int i0 = t, i1 = t + 1024;
        int a0 = (i0 >= off) ? pt[i0 - off] : 0;
        int c0 = (i0 >= off) ? ct[i0 - off] : 0;
        int a1 = (i1 >= off) ? pt[i1 - off] : 0;
        int c1 = (i1 >= off) ? ct[i1 - off] : 0;
        __syncthreads();
        pt[i0] += a0; ct[i0] += c0;
        pt[i1] += a1; ct[i1] += c1;
        __syncthreads();
    }
    for (int j = t; j < NB; j += 1024) {
        pairbase[j] = j ? pt[j - 1] : 0;
        colbase[j]  = j ? ct[j - 1] : 0;
    }
    if (t == 0) { pairbase[NB] = pt[NB - 1]; colbase[NB] = ct[NB - 1]; }
}

// K3: scatter tagged (src | localdst<<26) into bucket regions (4B entries).
__global__ __launch_bounds__(256) void bucket_scatter(
    const int* __restrict__ src, const int* __restrict__ dst, int E, int NB, int chunk,
    const int* __restrict__ hist2, const int* __restrict__ pairbase,
    unsigned* __restrict__ pairs)
{
    __shared__ int ofs[MAXNB];
    int b = blockIdx.x;
    for (int j = threadIdx.x; j < NB; j += 256)
        ofs[j] = hist2[HIDX(b, j)] + pairbase[j];
    __syncthreads();
    int beg = b * chunk, end = min(E, beg + chunk);
    for (int e = beg + threadIdx.x; e < end; e += 256) {
        int s = src[e], d = dst[e];
        int slot = atomicAdd(&ofs[d >> 6], 1);     // LDS atomic
        pairs[slot] = (unsigned)s | ((unsigned)(d & 63) << 26);
    }
}

// K4: per-bucket node-CSR: rp, dinv, self-loop, col scatter (col = pure src id).
__global__ __launch_bounds__(256) void bucket_csr(
    const unsigned* __restrict__ pairs, const int* __restrict__ pairbase,
    const int* __restrict__ colbase, int N, int E,
    int* __restrict__ rp, unsigned* __restrict__ col, float* __restrict__ dinv)
{
    __shared__ int cnt[64], fill[64], seg[64];
    int j = blockIdx.x;
    int t = threadIdx.x;
    if (t < 64) { cnt[t] = 0; fill[t] = 0; }
    __syncthreads();
    int beg = pairbase[j], end = pairbase[j + 1];
    int n0 = j << 6;
    for (int e = beg + t; e < end; e += 256)
        atomicAdd(&cnt[pairs[e] >> 26], 1);
    __syncthreads();
    if (t < 64) {
        int c = cnt[t];
        int v = c + 1;                 // + self-loop
#pragma unroll
        for (int off = 1; off < 64; off <<= 1) {
            int u = __shfl_up(v, off);
            if (t >= off) v += u;
        }
        int segb = colbase[j] + v - (c + 1);   // exclusive scan base
        int n = n0 + t;
        if (n < N) {
            seg[t] = segb;
            rp[n] = segb;
            dinv[n] = rsqrtf((float)(c + 1));
            col[segb + c] = (unsigned)n;       // self-loop at segment end
            if (n == N - 1) rp[N] = segb + c + 1;
        }
    }
    __syncthreads();
    for (int e = beg + t; e < end; e += 256) {
        unsigned pr = pairs[e];
        int ln = (int)(pr >> 26);
        int r = atomicAdd(&fill[ln], 1);       // LDS atomic
        col[seg[ln] + r] = pr & CMASK;
    }
}

// ------- W1 -> bf16, transposed [j][k], XOR-swizzled bytes (once) -------
__global__ void w1prep(const float* __restrict__ W1, unsigned char* __restrict__ W1t) {
    int tid = blockIdx.x * blockDim.x + threadIdx.x;   // tid = j*128 + k
    if (tid >= F * F) return;
    int j = tid >> 7, k = tid & 127;
    unsigned short w = f2bf(W1[k * F + j]);
    int ofs = (j << 8) + (((k << 1)) ^ ((j & 7) << 4));
    *reinterpret_cast<unsigned short*>(W1t + ofs) = w;
}

// ------- prescale: xsq[p][n][32] = fp8(dinv[n]*x[n][32p..32p+31]) -------
__global__ void prescale(const float* __restrict__ x, const float* __restrict__ dinv,
                         unsigned char* __restrict__ xsq, int N) {
    int i = blockIdx.x * blockDim.x + threadIdx.x;   // float4 group: n*32+g
    if (i >= N * 32) return;
    int n = i >> 5, g = i & 31;
    int p = g >> 3, q = g & 7;
    float d = dinv[n];
    float4 v = ((const float4*)x)[i];
    int r = __builtin_amdgcn_cvt_pk_fp8_f32(v.x * d, v.y * d, 0, false);
    r = __builtin_amdgcn_cvt_pk_fp8_f32(v.z * d, v.w * d, r, true);
    *reinterpret_cast<unsigned*>(xsq + (size_t)p * N * 32 + (size_t)n * 32 + 4 * q) = r;
}

#define ACC16(u) \
    acc0 += __builtin_amdgcn_cvt_pk_f32_fp8((u).x, false); \
    acc1 += __builtin_amdgcn_cvt_pk_f32_fp8((u).x, true);  \
    acc2 += __builtin_amdgcn_cvt_pk_f32_fp8((u).y, false); \
    acc3 += __builtin_amdgcn_cvt_pk_f32_fp8((u).y, true);  \
    acc4 += __builtin_amdgcn_cvt_pk_f32_fp8((u).z, false); \
    acc5 += __builtin_amdgcn_cvt_pk_f32_fp8((u).z, true);  \
    acc6 += __builtin_amdgcn_cvt_pk_f32_fp8((u).w, false); \
    acc7 += __builtin_amdgcn_cvt_pk_f32_fp8((u).w, true);

// ------- agg1 v8: lane-pair/16B loop; ONE PASS PER DISPATCH (kernel = pass) -------
__global__ __launch_bounds__(128, 4) void agg1(
    const unsigned char* __restrict__ xsq, const int* __restrict__ rp,
    const unsigned* __restrict__ col, const float* __restrict__ dinv,
    unsigned short* __restrict__ xa, int N, int p)
{
    int w = threadIdx.x >> 6, l = threadIdx.x & 63;
    int s = l >> 1;                        // node within wave (0..31)
    int c16 = l & 1;                       // which 16B half of the 32B quarter-row
    int node = blockIdx.x * 64 + w * 32 + s;
    const unsigned char* xsp = xsq + (size_t)p * N * 32;

    bool valid = node < N;
    int beg = valid ? rp[node] : 0;
    int end = valid ? rp[node + 1] : 0;
    int cnt = end - beg;
    const unsigned* cp = col + beg;
    int boff = c16 << 4;

    f32x2 acc0 = {0.f,0.f}, acc1 = {0.f,0.f}, acc2 = {0.f,0.f}, acc3 = {0.f,0.f};
    f32x2 acc4 = {0.f,0.f}, acc5 = {0.f,0.f}, acc6 = {0.f,0.f}, acc7 = {0.f,0.f};
    int k = 0;
    for (; k + 4 <= cnt; k += 4) {
        unsigned cv0 = cp[k], cv1 = cp[k+1], cv2 = cp[k+2], cv3 = cp[k+3];
        uint4 u0 = *reinterpret_cast<const uint4*>(xsp + ((size_t)cv0 << 5) + boff);
        uint4 u1 = *reinterpret_cast<const uint4*>(xsp + ((size_t)cv1 << 5) + boff);
        uint4 u2 = *reinterpret_cast<const uint4*>(xsp + ((size_t)cv2 << 5) + boff);
        uint4 u3 = *reinterpret_cast<const uint4*>(xsp + ((size_t)cv3 << 5) + boff);
        ACC16(u0) ACC16(u1) ACC16(u2) ACC16(u3)
    }
    for (; k < cnt; ++k) {
        unsigned cv = cp[k];
        uint4 u = *reinterpret_cast<const uint4*>(xsp + ((size_t)cv << 5) + boff);
        ACC16(u)
    }

    if (valid) {
        float d = dinv[node];
        unsigned q0 = pack2(acc0.x * d, acc0.y * d);
        unsigned q1 = pack2(acc1.x * d, acc1.y * d);
        unsigned q2 = pack2(acc2.x * d, acc2.y * d);
        unsigned q3 = pack2(acc3.x * d, acc3.y * d);
        unsigned q4 = pack2(acc4.x * d, acc4.y * d);
        unsigned q5 = pack2(acc5.x * d, acc5.y * d);
        unsigned q6 = pack2(acc6.x * d, acc6.y * d);
        unsigned q7 = pack2(acc7.x * d, acc7.y * d);
        unsigned short* op = xa + (size_t)node * F + p * 32 + (c16 << 4);
        *reinterpret_cast<uint4*>(op)     = make_uint4(q0, q1, q2, q3);
        *reinterpret_cast<uint4*>(op + 8) = make_uint4(q4, q5, q6, q7);
    }
}

// ------- MLP: h2s[i] = dinv_i * (relu(xa@W1 + b1) @ W2) via MFMA -------
__global__ __launch_bounds__(512) void mlp(
    const unsigned short* __restrict__ xa, const float* __restrict__ dinv,
    const float* __restrict__ b1, const float* __restrict__ W2,
    const unsigned char* __restrict__ W1t_g, float* __restrict__ h2s, int N)
{
    __shared__ unsigned char W1t[F * F * 2];   // 32 KB swizzled [j][k]
    __shared__ unsigned char XA[32 * 256];     // 8 KB swizzled [node][k]
    __shared__ float part[2][16][4];

    for (int idx = threadIdx.x; idx < (F * F * 2) / 16; idx += 512)
        ((int4*)W1t)[idx] = ((const int4*)W1t_g)[idx];

    {
        int r = threadIdx.x >> 4, t16 = threadIdx.x & 15;
        int gi = blockIdx.x * 32 + r;
        uint4 v = make_uint4(0, 0, 0, 0);
        if (gi < N) v = *reinterpret_cast<const uint4*>(xa + (size_t)gi * F + 8 * t16);
        *reinterpret_cast<uint4*>(XA + r * 256 + ((16 * t16) ^ ((r & 7) << 4))) = v;
    }
    __syncthreads();

    int wave = threadIdx.x >> 6, lane = threadIdx.x & 63;
    int g = wave >> 2, jt0 = (wave & 3) * 2;
    int l15 = lane & 15;
    int kb = (lane >> 4) * 16;

    bf16x8 afr[4];
    int arow = g * 16 + l15;
#pragma unroll
    for (int kk = 0; kk < 4; ++kk) {
        int ofs = arow * 256 + ((kk * 64 + kb) ^ ((arow & 7) << 4));
        afr[kk] = *reinterpret_cast<const bf16x8*>(XA + ofs);
    }

    float p[4] = {0.f, 0.f, 0.f, 0.f};
#pragma unroll
    for (int jj = 0; jj < 2; ++jj) {
        int j = (jt0 + jj) * 16 + l15;
        f32x4 d = {0.f, 0.f, 0.f, 0.f};
#pragma unroll
        for (int kk = 0; kk < 4; ++kk) {
            int ofs = j * 256 + ((kk * 64 + kb) ^ ((j & 7) << 4));
            bf16x8 bfr = *reinterpret_cast<const bf16x8*>(W1t + ofs);
            d = __builtin_amdgcn_mfma_f32_16x16x32_bf16(afr[kk], bfr, d, 0, 0, 0);
        }
        float bj = b1[j], wj = W2[j];
#pragma unroll
        for (int r = 0; r < 4; ++r) {
            float v = fmaxf(d[r] + bj, 0.f);
            p[r] += v * wj;
        }
    }
#pragma unroll
    for (int r = 0; r < 4; ++r) {
        p[r] += __shfl_xor(p[r], 1);
        p[r] += __shfl_xor(p[r], 2);
        p[r] += __shfl_xor(p[r], 4);
        p[r] += __shfl_xor(p[r], 8);
    }
    if (l15 == 0) {
#pragma unroll
        for (int r = 0; r < 4; ++r)
            part[g][(lane >> 4) * 4 + r][wave & 3] = p[r];
    }
    __syncthreads();

    if (threadIdx.x < 32) {
        int i = blockIdx.x * 32 + threadIdx.x;
        if (i < N) {
            const float* q = part[threadIdx.x >> 4][threadIdx.x & 15];
            h2s[i] = dinv[i] * (q[0] + q[1] + q[2] + q[3]);
        }
    }
}

// ------- layer 2 aggregation: quarter-wave (16 lanes) per node -------
__global__ __launch_bounds__(256) void agg2(
    const float* __restrict__ h2s, const int* __restrict__ rp,
    const unsigned* __restrict__ col, const float* __restrict__ dinv,
    const float* __restrict__ b2, float* __restrict__ h2, int N)
{
    int nid = (blockIdx.x * 256 + threadIdx.x) >> 4;
    int c = threadIdx.x & 15;
    if (nid >= N) return;
    int beg = rfl(rp[nid]);
    int end = rfl(rp[nid + 1]);
    float s = 0.f;
    for (int e = beg + c; e < end; e += 16)
        s += h2s[col[e]];
#pragma unroll
    for (int off = 8; off; off >>= 1) s += __shfl_xor(s, off);
    if (c == 0) h2[nid] = dinv[nid] * s + b2[0];
}

// ------- edge probabilities -------
__global__ void edge_probs(const int* __restrict__ src, const int* __restrict__ dst,
                           const float* __restrict__ h2, float* __restrict__ out, int E) {
    int e = blockIdx.x * blockDim.x + threadIdx.x;
    if (e >= E) return;
    float v = h2[src[e]] * h2[dst[e]];
    out[e] = 1.0f / (1.0f + __expf(-v));
}

// ---------------- launch ----------------

extern "C" void kernel_launch(void* const* d_in, const int* in_sizes, int n_in,
                              void* d_out, int out_size, void* d_ws, size_t ws_size,
                              hipStream_t stream) {
    const float* x  = (const float*)d_in[0];
    const int*   ei = (const int*)d_in[1];       // int32 (JAX x64 disabled)
    const float* W1 = (const float*)d_in[2];
    const float* b1 = (const float*)d_in[3];
    const float* W2 = (const float*)d_in[4];
    const float* b2 = (const float*)d_in[5];
    float* out = (float*)d_out;

    int N = in_sizes[0] / F;
    int E = in_sizes[1] / 2;
    const int* src = ei;
    const int* dst = ei + E;
    int total = E + N;
    int NB = (N + 63) >> 6;                      // buckets of 64 nodes (CSR build)
    int NT = (NB + 15) >> 4;                     // 16-bucket tiles
    int NBP = NT << 4;                           // padded bucket count
    int chunk = (E + NBLK - 1) / NBLK;

    // workspace; pairs (4B/edge) and xsq share one region
    char* ws = (char*)d_ws;
    size_t off = 0;
    auto alloc = [&](size_t bytes) -> void* {
        off = (off + 255) & ~(size_t)255;
        void* p = ws + off;
        off += bytes;
        return p;
    };
    float* dinv  = (float*)alloc((size_t)N * 4);
    int*   rp    = (int*)alloc((size_t)(N + 1) * 4);
    int*   hist2 = (int*)alloc((size_t)NT * NBLK * 16 * 4);
    int*   colbase  = (int*)alloc((size_t)(NB + 1) * 4);
    int*   pairbase = (int*)alloc((size_t)(NB + 1) * 4);
    int*   ptot  = (int*)alloc((size_t)NB * 4);
    int*   ctot  = (int*)alloc((size_t)NB * 4);
    unsigned* col = (unsigned*)alloc((size_t)total * 4);
    unsigned char* W1tg = (unsigned char*)alloc(F * F * 2);
    unsigned short* xa  = (unsigned short*)alloc((size_t)N * F * 2);
    float* h2s   = (float*)alloc((size_t)N * 4);
    float* h2    = (float*)alloc((size_t)N * 4);
    size_t uniBytes = (size_t)E * 4;             // pairs (tagged, 4B)
    size_t xsqBytes = (size_t)N * 32 * 4;
    if (xsqBytes > uniBytes) uniBytes = xsqBytes;
    void* uni = alloc(uniBytes);
    unsigned* pairs = (unsigned*)uni;
    unsigned char* xsq = (unsigned char*)uni;
    (void)ws_size;

    bucket_count<<<NBLK, 256, 0, stream>>>(dst, E, NBP, chunk, hist2);
    tile_scan<<<NT, 1024, 0, stream>>>(hist2, NB, N, ptot, ctot);
    base_scan<<<1, 1024, 0, stream>>>(ptot, ctot, NB, pairbase, colbase);
    bucket_scatter<<<NBLK, 256, 0, stream>>>(src, dst, E, NB, chunk, hist2, pairbase, pairs);
    bucket_csr<<<NB, 256, 0, stream>>>(pairs, pairbase, colbase, N, E, rp, col, dinv);
    w1prep<<<(F * F + 255) / 256, 256, 0, stream>>>(W1, W1tg);
    prescale<<<(N * 32 + 255) / 256, 256, 0, stream>>>(x, dinv, xsq, N);
    int nblk1 = (N + 63) / 64;
    for (int p = 0; p < 4; ++p)
        agg1<<<nblk1, 128, 0, stream>>>(xsq, rp, col, dinv, xa, N, p);
    mlp<<<(N + 31) / 32, 512, 0, stream>>>(xa, dinv, b1, W2, W1tg, h2s, N);
    agg2<<<((size_t)N * 16 + 255) / 256, 256, 0, stream>>>(h2s, rp, col, dinv, b2, h2, N);
    edge_probs<<<(E + 255) / 256, 256, 0, stream>>>(src, dst, h2, out, E);
}

// Round 14
// 261.116 us; speedup vs baseline: 1.0717x; 1.0641x over previous
//
#include <hip/hip_runtime.h>
#include <hip/hip_bf16.h>
#include <math.h>

#define F 128
#define NBLK 1024     // blocks for bucket_count / bucket_scatter
#define SBITS 9       // 512 nodes per super-bucket
#define SBSZ 512
#define NSBMAX 256    // max super-buckets (N <= 131072)
#define CHUNKMAX 4096 // max edges per scatter block
#define MAXNB 2048
#define SMASK 0x1FFFFu   // pairs payload mask (src id, 17 bits); bits 17.. = local dst
// hist2 tiled layout: [j/16][t][j%16]  -> every access line-coalesced
#define HIDX(b, j) ((((j) >> 4) * (NBLK * 16)) + ((b) * 16) + ((j) & 15))

typedef short bf16x8 __attribute__((ext_vector_type(8)));
typedef float f32x4 __attribute__((ext_vector_type(4)));
typedef float f32x2 __attribute__((ext_vector_type(2)));

__device__ __forceinline__ int rfl(int v) { return __builtin_amdgcn_readfirstlane(v); }
__device__ __forceinline__ unsigned short f2bf(float f) {
    __hip_bfloat16 h = __float2bfloat16(f);
    return *reinterpret_cast<unsigned short*>(&h);
}
__device__ __forceinline__ unsigned pack2(float lo, float hi) {
    return (unsigned)f2bf(lo) | ((unsigned)f2bf(hi) << 16);
}

// ---------------- CSR build via two-level counting sort ----------------

// K1: per-(block,superbucket) histogram.
__global__ __launch_bounds__(256) void bucket_count(
    const int* __restrict__ dst, int E, int NBP, int chunk, int* __restrict__ hist2)
{
    __shared__ int h[NSBMAX];
    for (int j = threadIdx.x; j < NBP; j += 256) h[j] = 0;
    __syncthreads();
    int b = blockIdx.x;
    int beg = b * chunk, end = min(E, beg + chunk);
    for (int e = beg + threadIdx.x; e < end; e += 256)
        atomicAdd(&h[dst[e] >> SBITS], 1);         // LDS atomic
    __syncthreads();
    for (int j = threadIdx.x; j < NBP; j += 256) hist2[HIDX(b, j)] = h[j];
}

// K2a: per-tile (16 buckets) scan over the 1024 block-counts, in place; totals out.
__global__ __launch_bounds__(1024) void tile_scan(
    int* __restrict__ hist2, int NB, int N,
    int* __restrict__ ptot, int* __restrict__ ctot)
{
    __shared__ int lds[64][16];
    int tile = blockIdx.x;
    int c = threadIdx.x >> 4, jj = threadIdx.x & 15;
    int j = tile * 16 + jj;
    int* base = hist2 + (size_t)tile * (NBLK * 16);
    int s = 0;
#pragma unroll
    for (int t = c * 16; t < c * 16 + 16; ++t) s += base[t * 16 + jj];
    lds[c][jj] = s;
    __syncthreads();
    for (int off = 1; off < 64; off <<= 1) {
        int v = (c >= off) ? lds[c - off][jj] : 0;
        __syncthreads();
        lds[c][jj] += v;
        __syncthreads();
    }
    int run = c ? lds[c - 1][jj] : 0;
#pragma unroll
    for (int t = c * 16; t < c * 16 + 16; ++t) {
        int v = base[t * 16 + jj];
        base[t * 16 + jj] = run;
        run += v;
    }
    if (c == 63 && j < NB) {
        int tot = lds[63][jj];
        ptot[j] = tot;
        int n0 = j << SBITS;
        int nodes = min(SBSZ, N - n0);
        ctot[j] = tot + nodes;           // + self-loops
    }
}

// K2b: exclusive scan of bucket totals -> pairbase / colbase.
__global__ __launch_bounds__(1024) void base_scan(
    const int* __restrict__ ptot, const int* __restrict__ ctot, int NB,
    int* __restrict__ pairbase, int* __restrict__ colbase)
{
    __shared__ int pt[MAXNB], ct[MAXNB];
    int t = threadIdx.x;
    for (int j = t; j < MAXNB; j += 1024) {
        pt[j] = (j < NB) ? ptot[j] : 0;
        ct[j] = (j < NB) ? ctot[j] : 0;
    }
    __syncthreads();
    for (int off = 1; off < MAXNB; off <<= 1) {
        int i0 = t, i1 = t + 1024;
        int a0 = (i0 >= off) ? pt[i0 - off] : 0;
        int c0 = (i0 >= off) ? ct[i0 - off] : 0;
        int a1 = (i1 >= off) ? pt[i1 - off] : 0;
        int c1 = (i1 >= off) ? ct[i1 - off] : 0;
        __syncthreads();
        pt[i0] += a0; ct[i0] += c0;
        pt[i1] += a1; ct[i1] += c1;
        __syncthreads();
    }
    for (int j = t; j < NB; j += 1024) {
        pairbase[j] = j ? pt[j - 1] : 0;
        colbase[j]  = j ? ct[j - 1] : 0;
    }
    if (t == 0) { pairbase[NB] = pt[NB - 1]; colbase[NB] = ct[NB - 1]; }
}

// K3: radix-partition scatter. LDS counting sort of the chunk, then linear
// write-out -> consecutive threads hit consecutive global addresses (64B runs).
__global__ __launch_bounds__(256) void bucket_scatter(
    const int* __restrict__ src, const int* __restrict__ dst, int E, int NSB, int chunk,
    const int* __restrict__ hist2, const int* __restrict__ pairbase,
    unsigned* __restrict__ pairs)
{
    __shared__ int start[NSBMAX + 1];
    __shared__ int cursor[NSBMAX];
    __shared__ int gbase[NSBMAX];
    __shared__ int scanbuf[256];
    __shared__ unsigned stage[CHUNKMAX];
    int b = blockIdx.x, t = threadIdx.x;
    for (int j = t; j < NSB; j += 256) {
        cursor[j] = 0;
        gbase[j] = hist2[HIDX(b, j)] + pairbase[j];
    }
    __syncthreads();
    int beg = b * chunk, end = min(E, beg + chunk);
    int cnt = end - beg;
    // phase 1: histogram
    for (int e = beg + t; e < end; e += 256)
        atomicAdd(&cursor[dst[e] >> SBITS], 1);
    __syncthreads();
    // phase 2: exclusive scan (NSB <= 256)
    int v = (t < NSB) ? cursor[t] : 0;
    scanbuf[t] = v;
    __syncthreads();
    for (int off = 1; off < 256; off <<= 1) {
        int u = (t >= off) ? scanbuf[t - off] : 0;
        __syncthreads();
        scanbuf[t] += u;
        __syncthreads();
    }
    if (t < NSB) { start[t] = scanbuf[t] - v; cursor[t] = 0; }
    if (t == 0) start[NSB] = cnt;
    __syncthreads();
    // phase 3: rank + stage (LDS sorted by bucket)
    for (int e = beg + t; e < end; e += 256) {
        int sv = src[e], d = dst[e];
        int sb = d >> SBITS;
        int r = atomicAdd(&cursor[sb], 1);
        stage[start[sb] + r] = (unsigned)sv | ((unsigned)(d & (SBSZ - 1)) << 17);
    }
    __syncthreads();
    // phase 4: linear write-out; bucket via binary search (8 steps)
    for (int i = t; i < cnt; i += 256) {
        int lo = 0, hi = NSB;
        while (hi - lo > 1) {
            int mid = (lo + hi) >> 1;
            if (start[mid] <= i) lo = mid; else hi = mid;
        }
        pairs[gbase[lo] + (i - start[lo])] = stage[i];
    }
}

// K4: per-superbucket node-CSR (512 nodes): rp, dinv, self-loop, col scatter.
__global__ __launch_bounds__(1024) void bucket_csr(
    const unsigned* __restrict__ pairs, const int* __restrict__ pairbase,
    const int* __restrict__ colbase, int N,
    int* __restrict__ rp, unsigned* __restrict__ col, float* __restrict__ dinv)
{
    __shared__ int cnt[SBSZ], fill[SBSZ], seg[SBSZ], scanb[SBSZ];
    int j = blockIdx.x, t = threadIdx.x;
    if (t < SBSZ) { cnt[t] = 0; fill[t] = 0; }
    __syncthreads();
    int beg = pairbase[j], end = pairbase[j + 1];
    int n0 = j << SBITS;
    for (int e = beg + t; e < end; e += 1024)
        atomicAdd(&cnt[pairs[e] >> 17], 1);
    __syncthreads();
    if (t < SBSZ) scanb[t] = cnt[t] + 1;   // + self-loop
    __syncthreads();
    for (int off = 1; off < SBSZ; off <<= 1) {
        int u = 0;
        if (t < SBSZ && t >= off) u = scanb[t - off];
        __syncthreads();
        if (t < SBSZ) scanb[t] += u;
        __syncthreads();
    }
    if (t < SBSZ) {
        int c = cnt[t];
        int segb = colbase[j] + scanb[t] - (c + 1);   // exclusive base
        int n = n0 + t;
        if (n < N) {
            seg[t] = segb;
            rp[n] = segb;
            dinv[n] = rsqrtf((float)(c + 1));
            col[segb + c] = (unsigned)n;               // self-loop at segment end
            if (n == N - 1) rp[N] = segb + c + 1;
        }
    }
    __syncthreads();
    for (int e = beg + t; e < end; e += 1024) {
        unsigned pr = pairs[e];
        int ln = (int)(pr >> 17);
        int r = atomicAdd(&fill[ln], 1);       // LDS atomic
        col[seg[ln] + r] = pr & SMASK;
    }
}

// ------- W1 -> bf16, transposed [j][k], XOR-swizzled bytes (once) -------
__global__ void w1prep(const float* __restrict__ W1, unsigned char* __restrict__ W1t) {
    int tid = blockIdx.x * blockDim.x + threadIdx.x;   // tid = j*128 + k
    if (tid >= F * F) return;
    int j = tid >> 7, k = tid & 127;
    unsigned short w = f2bf(W1[k * F + j]);
    int ofs = (j << 8) + (((k << 1)) ^ ((j & 7) << 4));
    *reinterpret_cast<unsigned short*>(W1t + ofs) = w;
}

// ------- prescale: xsq[p][n][32] = fp8(dinv[n]*x[n][32p..32p+31]) -------
__global__ void prescale(const float* __restrict__ x, const float* __restrict__ dinv,
                         unsigned char* __restrict__ xsq, int N) {
    int i = blockIdx.x * blockDim.x + threadIdx.x;   // float4 group: n*32+g
    if (i >= N * 32) return;
    int n = i >> 5, g = i & 31;
    int p = g >> 3, q = g & 7;
    float d = dinv[n];
    float4 v = ((const float4*)x)[i];
    int r = __builtin_amdgcn_cvt_pk_fp8_f32(v.x * d, v.y * d, 0, false);
    r = __builtin_amdgcn_cvt_pk_fp8_f32(v.z * d, v.w * d, r, true);
    *reinterpret_cast<unsigned*>(xsq + (size_t)p * N * 32 + (size_t)n * 32 + 4 * q) = r;
}

#define ACC16(u) \
    acc0 += __builtin_amdgcn_cvt_pk_f32_fp8((u).x, false); \
    acc1 += __builtin_amdgcn_cvt_pk_f32_fp8((u).x, true);  \
    acc2 += __builtin_amdgcn_cvt_pk_f32_fp8((u).y, false); \
    acc3 += __builtin_amdgcn_cvt_pk_f32_fp8((u).y, true);  \
    acc4 += __builtin_amdgcn_cvt_pk_f32_fp8((u).z, false); \
    acc5 += __builtin_amdgcn_cvt_pk_f32_fp8((u).z, true);  \
    acc6 += __builtin_amdgcn_cvt_pk_f32_fp8((u).w, false); \
    acc7 += __builtin_amdgcn_cvt_pk_f32_fp8((u).w, true);

// ------- agg1 v8: lane-pair/16B loop; ONE PASS PER DISPATCH (kernel = pass) -------
__global__ __launch_bounds__(128, 4) void agg1(
    const unsigned char* __restrict__ xsq, const int* __restrict__ rp,
    const unsigned* __restrict__ col, const float* __restrict__ dinv,
    unsigned short* __restrict__ xa, int N, int p)
{
    int w = threadIdx.x >> 6, l = threadIdx.x & 63;
    int s = l >> 1;                        // node within wave (0..31)
    int c16 = l & 1;                       // which 16B half of the 32B quarter-row
    int node = blockIdx.x * 64 + w * 32 + s;
    const unsigned char* xsp = xsq + (size_t)p * N * 32;

    bool valid = node < N;
    int beg = valid ? rp[node] : 0;
    int end = valid ? rp[node + 1] : 0;
    int cnt = end - beg;
    const unsigned* cp = col + beg;
    int boff = c16 << 4;

    f32x2 acc0 = {0.f,0.f}, acc1 = {0.f,0.f}, acc2 = {0.f,0.f}, acc3 = {0.f,0.f};
    f32x2 acc4 = {0.f,0.f}, acc5 = {0.f,0.f}, acc6 = {0.f,0.f}, acc7 = {0.f,0.f};
    int k = 0;
    for (; k + 4 <= cnt; k += 4) {
        unsigned cv0 = cp[k], cv1 = cp[k+1], cv2 = cp[k+2], cv3 = cp[k+3];
        uint4 u0 = *reinterpret_cast<const uint4*>(xsp + ((size_t)cv0 << 5) + boff);
        uint4 u1 = *reinterpret_cast<const uint4*>(xsp + ((size_t)cv1 << 5) + boff);
        uint4 u2 = *reinterpret_cast<const uint4*>(xsp + ((size_t)cv2 << 5) + boff);
        uint4 u3 = *reinterpret_cast<const uint4*>(xsp + ((size_t)cv3 << 5) + boff);
        ACC16(u0) ACC16(u1) ACC16(u2) ACC16(u3)
    }
    for (; k < cnt; ++k) {
        unsigned cv = cp[k];
        uint4 u = *reinterpret_cast<const uint4*>(xsp + ((size_t)cv << 5) + boff);
        ACC16(u)
    }

    if (valid) {
        float d = dinv[node];
        unsigned q0 = pack2(acc0.x * d, acc0.y * d);
        unsigned q1 = pack2(acc1.x * d, acc1.y * d);
        unsigned q2 = pack2(acc2.x * d, acc2.y * d);
        unsigned q3 = pack2(acc3.x * d, acc3.y * d);
        unsigned q4 = pack2(acc4.x * d, acc4.y * d);
        unsigned q5 = pack2(acc5.x * d, acc5.y * d);
        unsigned q6 = pack2(acc6.x * d, acc6.y * d);
        unsigned q7 = pack2(acc7.x * d, acc7.y * d);
        unsigned short* op = xa + (size_t)node * F + p * 32 + (c16 << 4);
        *reinterpret_cast<uint4*>(op)     = make_uint4(q0, q1, q2, q3);
        *reinterpret_cast<uint4*>(op + 8) = make_uint4(q4, q5, q6, q7);
    }
}

// ------- MLP: h2s[i] = dinv_i * (relu(xa@W1 + b1) @ W2) via MFMA -------
__global__ __launch_bounds__(512) void mlp(
    const unsigned short* __restrict__ xa, const float* __restrict__ dinv,
    const float* __restrict__ b1, const float* __restrict__ W2,
    const unsigned char* __restrict__ W1t_g, float* __restrict__ h2s, int N)
{
    __shared__ unsigned char W1t[F * F * 2];   // 32 KB swizzled [j][k]
    __shared__ unsigned char XA[32 * 256];     // 8 KB swizzled [node][k]
    __shared__ float part[2][16][4];

    for (int idx = threadIdx.x; idx < (F * F * 2) / 16; idx += 512)
        ((int4*)W1t)[idx] = ((const int4*)W1t_g)[idx];

    {
        int r = threadIdx.x >> 4, t16 = threadIdx.x & 15;
        int gi = blockIdx.x * 32 + r;
        uint4 v = make_uint4(0, 0, 0, 0);
        if (gi < N) v = *reinterpret_cast<const uint4*>(xa + (size_t)gi * F + 8 * t16);
        *reinterpret_cast<uint4*>(XA + r * 256 + ((16 * t16) ^ ((r & 7) << 4))) = v;
    }
    __syncthreads();

    int wave = threadIdx.x >> 6, lane = threadIdx.x & 63;
    int g = wave >> 2, jt0 = (wave & 3) * 2;
    int l15 = lane & 15;
    int kb = (lane >> 4) * 16;

    bf16x8 afr[4];
    int arow = g * 16 + l15;
#pragma unroll
    for (int kk = 0; kk < 4; ++kk) {
        int ofs = arow * 256 + ((kk * 64 + kb) ^ ((arow & 7) << 4));
        afr[kk] = *reinterpret_cast<const bf16x8*>(XA + ofs);
    }

    float p[4] = {0.f, 0.f, 0.f, 0.f};
#pragma unroll
    for (int jj = 0; jj < 2; ++jj) {
        int j = (jt0 + jj) * 16 + l15;
        f32x4 d = {0.f, 0.f, 0.f, 0.f};
#pragma unroll
        for (int kk = 0; kk < 4; ++kk) {
            int ofs = j * 256 + ((kk * 64 + kb) ^ ((j & 7) << 4));
            bf16x8 bfr = *reinterpret_cast<const bf16x8*>(W1t + ofs);
            d = __builtin_amdgcn_mfma_f32_16x16x32_bf16(afr[kk], bfr, d, 0, 0, 0);
        }
        float bj = b1[j], wj = W2[j];
#pragma unroll
        for (int r = 0; r < 4; ++r) {
            float v = fmaxf(d[r] + bj, 0.f);
            p[r] += v * wj;
        }
    }
#pragma unroll
    for (int r = 0; r < 4; ++r) {
        p[r] += __shfl_xor(p[r], 1);
        p[r] += __shfl_xor(p[r], 2);
        p[r] += __shfl_xor(p[r], 4);
        p[r] += __shfl_xor(p[r], 8);
    }
    if (l15 == 0) {
#pragma unroll
        for (int r = 0; r < 4; ++r)
            part[g][(lane >> 4) * 4 + r][wave & 3] = p[r];
    }
    __syncthreads();

    if (threadIdx.x < 32) {
        int i = blockIdx.x * 32 + threadIdx.x;
        if (i < N) {
            const float* q = part[threadIdx.x >> 4][threadIdx.x & 15];
            h2s[i] = dinv[i] * (q[0] + q[1] + q[2] + q[3]);
        }
    }
}

// ------- layer 2 aggregation: quarter-wave (16 lanes) per node -------
__global__ __launch_bounds__(256) void agg2(
    const float* __restrict__ h2s, const int* __restrict__ rp,
    const unsigned* __restrict__ col, const float* __restrict__ dinv,
    const float* __restrict__ b2, float* __restrict__ h2, int N)
{
    int nid = (blockIdx.x * 256 + threadIdx.x) >> 4;
    int c = threadIdx.x & 15;
    if (nid >= N) return;
    int beg = rfl(rp[nid]);
    int end = rfl(rp[nid + 1]);
    float s = 0.f;
    for (int e = beg + c; e < end; e += 16)
        s += h2s[col[e]];
#pragma unroll
    for (int off = 8; off; off >>= 1) s += __shfl_xor(s, off);
    if (c == 0) h2[nid] = dinv[nid] * s + b2[0];
}

// ------- edge probabilities -------
__global__ void edge_probs(const int* __restrict__ src, const int* __restrict__ dst,
                           const float* __restrict__ h2, float* __restrict__ out, int E) {
    int e = blockIdx.x * blockDim.x + threadIdx.x;
    if (e >= E) return;
    float v = h2[src[e]] * h2[dst[e]];
    out[e] = 1.0f / (1.0f + __expf(-v));
}

// ---------------- launch ----------------

extern "C" void kernel_launch(void* const* d_in, const int* in_sizes, int n_in,
                              void* d_out, int out_size, void* d_ws, size_t ws_size,
                              hipStream_t stream) {
    const float* x  = (const float*)d_in[0];
    const int*   ei = (const int*)d_in[1];       // int32 (JAX x64 disabled)
    const float* W1 = (const float*)d_in[2];
    const float* b1 = (const float*)d_in[3];
    const float* W2 = (const float*)d_in[4];
    const float* b2 = (const float*)d_in[5];
    float* out = (float*)d_out;

    int N = in_sizes[0] / F;
    int E = in_sizes[1] / 2;
    const int* src = ei;
    const int* dst = ei + E;
    int total = E + N;
    int NSB = (N + SBSZ - 1) >> SBITS;           // 512-node super-buckets
    int NT = (NSB + 15) >> 4;                    // 16-bucket tiles
    int NBP = NT << 4;                           // padded bucket count
    int chunk = (E + NBLK - 1) / NBLK;

    // workspace; pairs (4B/edge) and xsq share one region
    char* ws = (char*)d_ws;
    size_t off = 0;
    auto alloc = [&](size_t bytes) -> void* {
        off = (off + 255) & ~(size_t)255;
        void* p = ws + off;
        off += bytes;
        return p;
    };
    float* dinv  = (float*)alloc((size_t)N * 4);
    int*   rp    = (int*)alloc((size_t)(N + 1) * 4);
    int*   hist2 = (int*)alloc((size_t)NT * NBLK * 16 * 4);
    int*   colbase  = (int*)alloc((size_t)(NSB + 1) * 4);
    int*   pairbase = (int*)alloc((size_t)(NSB + 1) * 4);
    int*   ptot  = (int*)alloc((size_t)NSB * 4);
    int*   ctot  = (int*)alloc((size_t)NSB * 4);
    unsigned* col = (unsigned*)alloc((size_t)total * 4);
    unsigned char* W1tg = (unsigned char*)alloc(F * F * 2);
    unsigned short* xa  = (unsigned short*)alloc((size_t)N * F * 2);
    float* h2s   = (float*)alloc((size_t)N * 4);
    float* h2    = (float*)alloc((size_t)N * 4);
    size_t uniBytes = (size_t)E * 4;             // pairs (tagged, 4B)
    size_t xsqBytes = (size_t)N * 32 * 4;
    if (xsqBytes > uniBytes) uniBytes = xsqBytes;
    void* uni = alloc(uniBytes);
    unsigned* pairs = (unsigned*)uni;
    unsigned char* xsq = (unsigned char*)uni;
    (void)ws_size;

    bucket_count<<<NBLK, 256, 0, stream>>>(dst, E, NBP, chunk, hist2);
    tile_scan<<<NT, 1024, 0, stream>>>(hist2, NSB, N, ptot, ctot);
    base_scan<<<1, 1024, 0, stream>>>(ptot, ctot, NSB, pairbase, colbase);
    bucket_scatter<<<NBLK, 256, 0, stream>>>(src, dst, E, NSB, chunk, hist2, pairbase, pairs);
    bucket_csr<<<NSB, 1024, 0, stream>>>(pairs, pairbase, colbase, N, rp, col, dinv);
    w1prep<<<(F * F + 255) / 256, 256, 0, stream>>>(W1, W1tg);
    prescale<<<(N * 32 + 255) / 256, 256, 0, stream>>>(x, dinv, xsq, N);
    int nblk1 = (N + 63) / 64;
    for (int p = 0; p < 4; ++p)
        agg1<<<nblk1, 128, 0, stream>>>(xsq, rp, col, dinv, xa, N, p);
    mlp<<<(N + 31) / 32, 512, 0, stream>>>(xa, dinv, b1, W2, W1tg, h2s, N);
    agg2<<<((size_t)N * 16 + 255) / 256, 256, 0, stream>>>(h2s, rp, col, dinv, b2, h2, N);
    edge_probs<<<(E + 255) / 256, 256, 0, stream>>>(src, dst, h2, out, E);
}

// Round 15
// 252.614 us; speedup vs baseline: 1.1078x; 1.0337x over previous
//
#include <hip/hip_runtime.h>
#include <hip/hip_bf16.h>
#include <math.h>

#define F 128
#define NBLK 1024     // blocks for bucket_count / bucket_scatter
#define SBITS 9       // 512 nodes per super-bucket
#define SBSZ 512
#define NSBMAX 256    // max super-buckets (N <= 131072)
#define CHUNKMAX 4096 // max edges per scatter block
#define MAXNB 2048
#define SMASK 0x1FFFFu   // pairs payload mask (src id, 17 bits); bits 17.. = local dst
// hist2 tiled layout: [j/16][t][j%16]  -> every access line-coalesced
#define HIDX(b, j) ((((j) >> 4) * (NBLK * 16)) + ((b) * 16) + ((j) & 15))

typedef short bf16x8 __attribute__((ext_vector_type(8)));
typedef float f32x4 __attribute__((ext_vector_type(4)));
typedef float f32x2 __attribute__((ext_vector_type(2)));

__device__ __forceinline__ int rfl(int v) { return __builtin_amdgcn_readfirstlane(v); }
__device__ __forceinline__ unsigned short f2bf(float f) {
    __hip_bfloat16 h = __float2bfloat16(f);
    return *reinterpret_cast<unsigned short*>(&h);
}
__device__ __forceinline__ unsigned pack2(float lo, float hi) {
    return (unsigned)f2bf(lo) | ((unsigned)f2bf(hi) << 16);
}

// ---------------- CSR build via two-level counting sort ----------------

// K1: per-(block,superbucket) histogram.
__global__ __launch_bounds__(256) void bucket_count(
    const int* __restrict__ dst, int E, int NBP, int chunk, int* __restrict__ hist2)
{
    __shared__ int h[NSBMAX];
    for (int j = threadIdx.x; j < NBP; j += 256) h[j] = 0;
    __syncthreads();
    int b = blockIdx.x;
    int beg = b * chunk, end = min(E, beg + chunk);
    for (int e = beg + threadIdx.x; e < end; e += 256)
        atomicAdd(&h[dst[e] >> SBITS], 1);         // LDS atomic
    __syncthreads();
    for (int j = threadIdx.x; j < NBP; j += 256) hist2[HIDX(b, j)] = h[j];
}

// K2a: per-tile (16 buckets) scan over the 1024 block-counts, in place; totals out.
__global__ __launch_bounds__(1024) void tile_scan(
    int* __restrict__ hist2, int NB, int N,
    int* __restrict__ ptot, int* __restrict__ ctot)
{
    __shared__ int lds[64][16];
    int tile = blockIdx.x;
    int c = threadIdx.x >> 4, jj = threadIdx.x & 15;
    int j = tile * 16 + jj;
    int* base = hist2 + (size_t)tile * (NBLK * 16);
    int s = 0;
#pragma unroll
    for (int t = c * 16; t < c * 16 + 16; ++t) s += base[t * 16 + jj];
    lds[c][jj] = s;
    __syncthreads();
    for (int off = 1; off < 64; off <<= 1) {
        int v = (c >= off) ? lds[c - off][jj] : 0;
        __syncthreads();
        lds[c][jj] += v;
        __syncthreads();
    }
    int run = c ? lds[c - 1][jj] : 0;
#pragma unroll
    for (int t = c * 16; t < c * 16 + 16; ++t) {
        int v = base[t * 16 + jj];
        base[t * 16 + jj] = run;
        run += v;
    }
    if (c == 63 && j < NB) {
        int tot = lds[63][jj];
        ptot[j] = tot;
        int n0 = j << SBITS;
        int nodes = min(SBSZ, N - n0);
        ctot[j] = tot + nodes;           // + self-loops
    }
}

// K2b: exclusive scan of bucket totals -> pairbase / colbase.
__global__ __launch_bounds__(1024) void base_scan(
    const int* __restrict__ ptot, const int* __restrict__ ctot, int NB,
    int* __restrict__ pairbase, int* __restrict__ colbase)
{
    __shared__ int pt[MAXNB], ct[MAXNB];
    int t = threadIdx.x;
    for (int j = t; j < MAXNB; j += 1024) {
        pt[j] = (j < NB) ? ptot[j] : 0;
        ct[j] = (j < NB) ? ctot[j] : 0;
    }
    __syncthreads();
    for (int off = 1; off < MAXNB; off <<= 1) {
        int i0 = t, i1 = t + 1024;
        int a0 = (i0 >= off) ? pt[i0 - off] : 0;
        int c0 = (i0 >= off) ? ct[i0 - off] : 0;
        int a1 = (i1 >= off) ? pt[i1 - off] : 0;
        int c1 = (i1 >= off) ? ct[i1 - off] : 0;
        __syncthreads();
        pt[i0] += a0; ct[i0] += c0;
        pt[i1] += a1; ct[i1] += c1;
        __syncthreads();
    }
    for (int j = t; j < NB; j += 1024) {
        pairbase[j] = j ? pt[j - 1] : 0;
        colbase[j]  = j ? ct[j - 1] : 0;
    }
    if (t == 0) { pairbase[NB] = pt[NB - 1]; colbase[NB] = ct[NB - 1]; }
}

// K3: radix-partition scatter. LDS counting sort of the chunk, then linear
// write-out -> consecutive threads hit consecutive global addresses (64B runs).
__global__ __launch_bounds__(256) void bucket_scatter(
    const int* __restrict__ src, const int* __restrict__ dst, int E, int NSB, int chunk,
    const int* __restrict__ hist2, const int* __restrict__ pairbase,
    unsigned* __restrict__ pairs)
{
    __shared__ int start[NSBMAX + 1];
    __shared__ int cursor[NSBMAX];
    __shared__ int gbase[NSBMAX];
    __shared__ int scanbuf[256];
    __shared__ unsigned stage[CHUNKMAX];
    int b = blockIdx.x, t = threadIdx.x;
    for (int j = t; j < NSB; j += 256) {
        cursor[j] = 0;
        gbase[j] = hist2[HIDX(b, j)] + pairbase[j];
    }
    __syncthreads();
    int beg = b * chunk, end = min(E, beg + chunk);
    int cnt = end - beg;
    // phase 1: histogram
    for (int e = beg + t; e < end; e += 256)
        atomicAdd(&cursor[dst[e] >> SBITS], 1);
    __syncthreads();
    // phase 2: exclusive scan (NSB <= 256)
    int v = (t < NSB) ? cursor[t] : 0;
    scanbuf[t] = v;
    __syncthreads();
    for (int off = 1; off < 256; off <<= 1) {
        int u = (t >= off) ? scanbuf[t - off] : 0;
        __syncthreads();
        scanbuf[t] += u;
        __syncthreads();
    }
    if (t < NSB) { start[t] = scanbuf[t] - v; cursor[t] = 0; }
    if (t == 0) start[NSB] = cnt;
    __syncthreads();
    // phase 3: rank + stage (LDS sorted by bucket)
    for (int e = beg + t; e < end; e += 256) {
        int sv = src[e], d = dst[e];
        int sb = d >> SBITS;
        int r = atomicAdd(&cursor[sb], 1);
        stage[start[sb] + r] = (unsigned)sv | ((unsigned)(d & (SBSZ - 1)) << 17);
    }
    __syncthreads();
    // phase 4: linear write-out; bucket via binary search (8 steps)
    for (int i = t; i < cnt; i += 256) {
        int lo = 0, hi = NSB;
        while (hi - lo > 1) {
            int mid = (lo + hi) >> 1;
            if (start[mid] <= i) lo = mid; else hi = mid;
        }
        pairs[gbase[lo] + (i - start[lo])] = stage[i];
    }
}

// K4: per-superbucket node-CSR (512 nodes): rp, dinv, self-loop, col scatter.
__global__ __launch_bounds__(1024) void bucket_csr(
    const unsigned* __restrict__ pairs, const int* __restrict__ pairbase,
    const int* __restrict__ colbase, int N,
    int* __restrict__ rp, unsigned* __restrict__ col, float* __restrict__ dinv)
{
    __shared__ int cnt[SBSZ], fill[SBSZ], seg[SBSZ], scanb[SBSZ];
    int j = blockIdx.x, t = threadIdx.x;
    if (t < SBSZ) { cnt[t] = 0; fill[t] = 0; }
    __syncthreads();
    int beg = pairbase[j], end = pairbase[j + 1];
    int n0 = j << SBITS;
    for (int e = beg + t; e < end; e += 1024)
        atomicAdd(&cnt[pairs[e] >> 17], 1);
    __syncthreads();
    if (t < SBSZ) scanb[t] = cnt[t] + 1;   // + self-loop
    __syncthreads();
    for (int off = 1; off < SBSZ; off <<= 1) {
        int u = 0;
        if (t < SBSZ && t >= off) u = scanb[t - off];
        __syncthreads();
        if (t < SBSZ) scanb[t] += u;
        __syncthreads();
    }
    if (t < SBSZ) {
        int c = cnt[t];
        int segb = colbase[j] + scanb[t] - (c + 1);   // exclusive base
        int n = n0 + t;
        if (n < N) {
            seg[t] = segb;
            rp[n] = segb;
            dinv[n] = rsqrtf((float)(c + 1));
            col[segb + c] = (unsigned)n;               // self-loop at segment end
            if (n == N - 1) rp[N] = segb + c + 1;
        }
    }
    __syncthreads();
    for (int e = beg + t; e < end; e += 1024) {
        unsigned pr = pairs[e];
        int ln = (int)(pr >> 17);
        int r = atomicAdd(&fill[ln], 1);       // LDS atomic
        col[seg[ln] + r] = pr & SMASK;
    }
}

// ------- W1 -> bf16, transposed [j][k], XOR-swizzled bytes (once) -------
__global__ void w1prep(const float* __restrict__ W1, unsigned char* __restrict__ W1t) {
    int tid = blockIdx.x * blockDim.x + threadIdx.x;   // tid = j*128 + k
    if (tid >= F * F) return;
    int j = tid >> 7, k = tid & 127;
    unsigned short w = f2bf(W1[k * F + j]);
    int ofs = (j << 8) + (((k << 1)) ^ ((j & 7) << 4));
    *reinterpret_cast<unsigned short*>(W1t + ofs) = w;
}

// ------- prescale: xsq[p][n][32] = fp8(dinv[n]*x[n][32p..32p+31]) -------
__global__ void prescale(const float* __restrict__ x, const float* __restrict__ dinv,
                         unsigned char* __restrict__ xsq, int N) {
    int i = blockIdx.x * blockDim.x + threadIdx.x;   // float4 group: n*32+g
    if (i >= N * 32) return;
    int n = i >> 5, g = i & 31;
    int p = g >> 3, q = g & 7;
    float d = dinv[n];
    float4 v = ((const float4*)x)[i];
    int r = __builtin_amdgcn_cvt_pk_fp8_f32(v.x * d, v.y * d, 0, false);
    r = __builtin_amdgcn_cvt_pk_fp8_f32(v.z * d, v.w * d, r, true);
    *reinterpret_cast<unsigned*>(xsq + (size_t)p * N * 32 + (size_t)n * 32 + 4 * q) = r;
}

#define ACC8(u) \
    a0 += __builtin_amdgcn_cvt_pk_f32_fp8((u).x, false); \
    a1 += __builtin_amdgcn_cvt_pk_f32_fp8((u).x, true);  \
    a2 += __builtin_amdgcn_cvt_pk_f32_fp8((u).y, false); \
    a3 += __builtin_amdgcn_cvt_pk_f32_fp8((u).y, true);

// ------- agg1 v9: lane-quad per node, 8B loads, x8 unroll; one pass/dispatch -------
// 4 lanes own one node (each lane 8 of the 32 quarter-feats). 16 nodes/wave ->
// 6250 waves/pass = ~6/SIMD (2x v8's TLP); 8 gathers in flight per lane (ILP).
// Kernel boundary still guarantees one 3.2MB xsq quarter live chip-wide.
__global__ __launch_bounds__(256, 4) void agg1(
    const unsigned char* __restrict__ xsq, const int* __restrict__ rp,
    const unsigned* __restrict__ col, const float* __restrict__ dinv,
    unsigned short* __restrict__ xa, int N, int p)
{
    int t = threadIdx.x;
    int node = blockIdx.x * 64 + (t >> 2);
    int sub = t & 3;                       // which 8B of the 32B quarter-row
    const unsigned char* xsp = xsq + (size_t)p * N * 32;

    bool valid = node < N;
    int beg = valid ? rp[node] : 0;
    int end = valid ? rp[node + 1] : 0;
    int cnt = end - beg;
    const unsigned* cp = col + beg;
    int boff = sub << 3;

    f32x2 a0 = {0.f,0.f}, a1 = {0.f,0.f}, a2 = {0.f,0.f}, a3 = {0.f,0.f};
    int k = 0;
    for (; k + 8 <= cnt; k += 8) {
        unsigned c0 = cp[k],   c1 = cp[k+1], c2 = cp[k+2], c3 = cp[k+3];
        unsigned c4 = cp[k+4], c5 = cp[k+5], c6 = cp[k+6], c7 = cp[k+7];
        uint2 u0 = *reinterpret_cast<const uint2*>(xsp + ((size_t)c0 << 5) + boff);
        uint2 u1 = *reinterpret_cast<const uint2*>(xsp + ((size_t)c1 << 5) + boff);
        uint2 u2 = *reinterpret_cast<const uint2*>(xsp + ((size_t)c2 << 5) + boff);
        uint2 u3 = *reinterpret_cast<const uint2*>(xsp + ((size_t)c3 << 5) + boff);
        uint2 u4 = *reinterpret_cast<const uint2*>(xsp + ((size_t)c4 << 5) + boff);
        uint2 u5 = *reinterpret_cast<const uint2*>(xsp + ((size_t)c5 << 5) + boff);
        uint2 u6 = *reinterpret_cast<const uint2*>(xsp + ((size_t)c6 << 5) + boff);
        uint2 u7 = *reinterpret_cast<const uint2*>(xsp + ((size_t)c7 << 5) + boff);
        ACC8(u0) ACC8(u1) ACC8(u2) ACC8(u3) ACC8(u4) ACC8(u5) ACC8(u6) ACC8(u7)
    }
    for (; k < cnt; ++k) {
        unsigned cv = cp[k];
        uint2 u = *reinterpret_cast<const uint2*>(xsp + ((size_t)cv << 5) + boff);
        ACC8(u)
    }

    if (valid) {
        float d = dinv[node];
        unsigned q0 = pack2(a0.x * d, a0.y * d);
        unsigned q1 = pack2(a1.x * d, a1.y * d);
        unsigned q2 = pack2(a2.x * d, a2.y * d);
        unsigned q3 = pack2(a3.x * d, a3.y * d);
        unsigned short* op = xa + (size_t)node * F + p * 32 + (sub << 3);
        *reinterpret_cast<uint4*>(op) = make_uint4(q0, q1, q2, q3);
    }
}

// ------- MLP: h2s[i] = dinv_i * (relu(xa@W1 + b1) @ W2) via MFMA -------
__global__ __launch_bounds__(512) void mlp(
    const unsigned short* __restrict__ xa, const float* __restrict__ dinv,
    const float* __restrict__ b1, const float* __restrict__ W2,
    const unsigned char* __restrict__ W1t_g, float* __restrict__ h2s, int N)
{
    __shared__ unsigned char W1t[F * F * 2];   // 32 KB swizzled [j][k]
    __shared__ unsigned char XA[32 * 256];     // 8 KB swizzled [node][k]
    __shared__ float part[2][16][4];

    for (int idx = threadIdx.x; idx < (F * F * 2) / 16; idx += 512)
        ((int4*)W1t)[idx] = ((const int4*)W1t_g)[idx];

    {
        int r = threadIdx.x >> 4, t16 = threadIdx.x & 15;
        int gi = blockIdx.x * 32 + r;
        uint4 v = make_uint4(0, 0, 0, 0);
        if (gi < N) v = *reinterpret_cast<const uint4*>(xa + (size_t)gi * F + 8 * t16);
        *reinterpret_cast<uint4*>(XA + r * 256 + ((16 * t16) ^ ((r & 7) << 4))) = v;
    }
    __syncthreads();

    int wave = threadIdx.x >> 6, lane = threadIdx.x & 63;
    int g = wave >> 2, jt0 = (wave & 3) * 2;
    int l15 = lane & 15;
    int kb = (lane >> 4) * 16;

    bf16x8 afr[4];
    int arow = g * 16 + l15;
#pragma unroll
    for (int kk = 0; kk < 4; ++kk) {
        int ofs = arow * 256 + ((kk * 64 + kb) ^ ((arow & 7) << 4));
        afr[kk] = *reinterpret_cast<const bf16x8*>(XA + ofs);
    }

    float p[4] = {0.f, 0.f, 0.f, 0.f};
#pragma unroll
    for (int jj = 0; jj < 2; ++jj) {
        int j = (jt0 + jj) * 16 + l15;
        f32x4 d = {0.f, 0.f, 0.f, 0.f};
#pragma unroll
        for (int kk = 0; kk < 4; ++kk) {
            int ofs = j * 256 + ((kk * 64 + kb) ^ ((j & 7) << 4));
            bf16x8 bfr = *reinterpret_cast<const bf16x8*>(W1t + ofs);
            d = __builtin_amdgcn_mfma_f32_16x16x32_bf16(afr[kk], bfr, d, 0, 0, 0);
        }
        float bj = b1[j], wj = W2[j];
#pragma unroll
        for (int r = 0; r < 4; ++r) {
            float v = fmaxf(d[r] + bj, 0.f);
            p[r] += v * wj;
        }
    }
#pragma unroll
    for (int r = 0; r < 4; ++r) {
        p[r] += __shfl_xor(p[r], 1);
        p[r] += __shfl_xor(p[r], 2);
        p[r] += __shfl_xor(p[r], 4);
        p[r] += __shfl_xor(p[r], 8);
    }
    if (l15 == 0) {
#pragma unroll
        for (int r = 0; r < 4; ++r)
            part[g][(lane >> 4) * 4 + r][wave & 3] = p[r];
    }
    __syncthreads();

    if (threadIdx.x < 32) {
        int i = blockIdx.x * 32 + threadIdx.x;
        if (i < N) {
            const float* q = part[threadIdx.x >> 4][threadIdx.x & 15];
            h2s[i] = dinv[i] * (q[0] + q[1] + q[2] + q[3]);
        }
    }
}

// ------- layer 2 aggregation: quarter-wave (16 lanes) per node -------
__global__ __launch_bounds__(256) void agg2(
    const float* __restrict__ h2s, const int* __restrict__ rp,
    const unsigned* __restrict__ col, const float* __restrict__ dinv,
    const float* __restrict__ b2, float* __restrict__ h2, int N)
{
    int nid = (blockIdx.x * 256 + threadIdx.x) >> 4;
    int c = threadIdx.x & 15;
    if (nid >= N) return;
    int beg = rfl(rp[nid]);
    int end = rfl(rp[nid + 1]);
    float s = 0.f;
    for (int e = beg + c; e < end; e += 16)
        s += h2s[col[e]];
#pragma unroll
    for (int off = 8; off; off >>= 1) s += __shfl_xor(s, off);
    if (c == 0) h2[nid] = dinv[nid] * s + b2[0];
}

// ------- edge probabilities -------
__global__ void edge_probs(const int* __restrict__ src, const int* __restrict__ dst,
                           const float* __restrict__ h2, float* __restrict__ out, int E) {
    int e = blockIdx.x * blockDim.x + threadIdx.x;
    if (e >= E) return;
    float v = h2[src[e]] * h2[dst[e]];
    out[e] = 1.0f / (1.0f + __expf(-v));
}

// ---------------- launch ----------------

extern "C" void kernel_launch(void* const* d_in, const int* in_sizes, int n_in,
                              void* d_out, int out_size, void* d_ws, size_t ws_size,
                              hipStream_t stream) {
    const float* x  = (const float*)d_in[0];
    const int*   ei = (const int*)d_in[1];       // int32 (JAX x64 disabled)
    const float* W1 = (const float*)d_in[2];
    const float* b1 = (const float*)d_in[3];
    const float* W2 = (const float*)d_in[4];
    const float* b2 = (const float*)d_in[5];
    float* out = (float*)d_out;

    int N = in_sizes[0] / F;
    int E = in_sizes[1] / 2;
    const int* src = ei;
    const int* dst = ei + E;
    int total = E + N;
    int NSB = (N + SBSZ - 1) >> SBITS;           // 512-node super-buckets
    int NT = (NSB + 15) >> 4;                    // 16-bucket tiles
    int NBP = NT << 4;                           // padded bucket count
    int chunk = (E + NBLK - 1) / NBLK;

    // workspace; pairs (4B/edge) and xsq share one region
    char* ws = (char*)d_ws;
    size_t off = 0;
    auto alloc = [&](size_t bytes) -> void* {
        off = (off + 255) & ~(size_t)255;
        void* p = ws + off;
        off += bytes;
        return p;
    };
    float* dinv  = (float*)alloc((size_t)N * 4);
    int*   rp    = (int*)alloc((size_t)(N + 1) * 4);
    int*   hist2 = (int*)alloc((size_t)NT * NBLK * 16 * 4);
    int*   colbase  = (int*)alloc((size_t)(NSB + 1) * 4);
    int*   pairbase = (int*)alloc((size_t)(NSB + 1) * 4);
    int*   ptot  = (int*)alloc((size_t)NSB * 4);
    int*   ctot  = (int*)alloc((size_t)NSB * 4);
    unsigned* col = (unsigned*)alloc((size_t)total * 4);
    unsigned char* W1tg = (unsigned char*)alloc(F * F * 2);
    unsigned short* xa  = (unsigned short*)alloc((size_t)N * F * 2);
    float* h2s   = (float*)alloc((size_t)N * 4);
    float* h2    = (float*)alloc((size_t)N * 4);
    size_t uniBytes = (size_t)E * 4;             // pairs (tagged, 4B)
    size_t xsqBytes = (size_t)N * 32 * 4;
    if (xsqBytes > uniBytes) uniBytes = xsqBytes;
    void* uni = alloc(uniBytes);
    unsigned* pairs = (unsigned*)uni;
    unsigned char* xsq = (unsigned char*)uni;
    (void)ws_size;

    bucket_count<<<NBLK, 256, 0, stream>>>(dst, E, NBP, chunk, hist2);
    tile_scan<<<NT, 1024, 0, stream>>>(hist2, NSB, N, ptot, ctot);
    base_scan<<<1, 1024, 0, stream>>>(ptot, ctot, NSB, pairbase, colbase);
    bucket_scatter<<<NBLK, 256, 0, stream>>>(src, dst, E, NSB, chunk, hist2, pairbase, pairs);
    bucket_csr<<<NSB, 1024, 0, stream>>>(pairs, pairbase, colbase, N, rp, col, dinv);
    w1prep<<<(F * F + 255) / 256, 256, 0, stream>>>(W1, W1tg);
    prescale<<<(N * 32 + 255) / 256, 256, 0, stream>>>(x, dinv, xsq, N);
    int nblk1 = (N + 63) / 64;
    for (int p = 0; p < 4; ++p)
        agg1<<<nblk1, 256, 0, stream>>>(xsq, rp, col, dinv, xa, N, p);
    mlp<<<(N + 31) / 32, 512, 0, stream>>>(xa, dinv, b1, W2, W1tg, h2s, N);
    agg2<<<((size_t)N * 16 + 255) / 256, 256, 0, stream>>>(h2s, rp, col, dinv, b2, h2, N);
    edge_probs<<<(E + 255) / 256, 256, 0, stream>>>(src, dst, h2, out, E);
}